// Round 10
// baseline (389.415 us; speedup 1.0000x reference)
//
#include <hip/hip_runtime.h>

// HSTU block, B=2 S=2048 D=1024 H=8 head=64 L=2. Inputs/outputs fp32.
// ws (62 MB): xf f32(16M) | h bf16(8M, aliased by vT 4M after gemm_silu)
//  | udot bf16(4M) | projh bf16(16M) | uvqkT bf16(8M) | owh bf16(2M) | opart f32(8M)
#define B_ 2
#define S_ 2048
#define D_ 1024
#define H_ 8
#define L_ 2
#define P_ 2048   // proj dim
#define F_ 512    // DL*H
#define R_ (B_*S_)

typedef unsigned short u16;
typedef unsigned int u32;
typedef __bf16 bf16;
typedef bf16 bf16x8 __attribute__((ext_vector_type(8)));
typedef short short8 __attribute__((ext_vector_type(8)));
typedef float v4f __attribute__((ext_vector_type(4)));

__device__ __forceinline__ float silu_fast(float x){
  float e = __expf(-x);
  return x * __builtin_amdgcn_rcpf(1.0f + e);
}
__device__ __forceinline__ float bf2f(u16 u){
  union { u32 i; float f; } x; x.i = ((u32)u) << 16; return x.f;
}
__device__ __forceinline__ u16 f2bfu(float f){
  union { float f; u32 i; } x; x.f = f;
  u32 r = x.i + 0x7fff + ((x.i >> 16) & 1);   // RNE
  return (u16)(r >> 16);
}
__device__ __forceinline__ void gload16(const u16* g, u16* l){
  __builtin_amdgcn_global_load_lds(
      (const __attribute__((address_space(1))) void*)g,
      (__attribute__((address_space(3))) void*)l, 16, 0, 0);
}

// ---- x copy ----
__global__ __launch_bounds__(256) void cvt_kernel(const float* __restrict__ x, float* __restrict__ xf){
  int i = (blockIdx.x * 256 + threadIdx.x) * 4;
  *(float4*)(xf + i) = *(const float4*)(x + i);
}

// ---- zero fp32 buffer ----
__global__ __launch_bounds__(256) void zero_kernel(float* __restrict__ p){
  int i = (blockIdx.x * 256 + threadIdx.x) * 4;
  *(float4*)(p + i) = make_float4(0.f, 0.f, 0.f, 0.f);
}

// ---- fp32 -> bf16 elementwise (o_w) ----
__global__ __launch_bounds__(256) void cvt_bf16_kernel(const float* __restrict__ src, u16* __restrict__ dst){
  int i = (blockIdx.x * 256 + threadIdx.x) * 4;
  float4 v = *(const float4*)(src + i);
  ushort4 o; o.x = f2bfu(v.x); o.y = f2bfu(v.y); o.z = f2bfu(v.z); o.w = f2bfu(v.w);
  *(ushort4*)(dst + i) = o;
}

// ---- uvqk (L,D,P) f32 -> uvqkT (L,P,D) bf16 ----
__global__ __launch_bounds__(256) void cvt_uvqkT_kernel(const float* __restrict__ uvqk, u16* __restrict__ ot){
  __shared__ float t[32][33];
  int l = blockIdx.z;
  int p0 = blockIdx.x * 32, d0 = blockIdx.y * 32;
  int tx = threadIdx.x & 31, ty = threadIdx.x >> 5;   // ty: 8 rows/pass
  const float* src = uvqk + ((size_t)l * D_ + d0) * P_ + p0;
  #pragma unroll
  for (int s = 0; s < 4; s++)
    t[ty + s*8][tx] = src[(size_t)(ty + s*8) * P_ + tx];
  __syncthreads();
  u16* dst = ot + ((size_t)l * P_ + p0) * D_ + d0;
  #pragma unroll
  for (int s = 0; s < 4; s++)
    dst[(size_t)(ty + s*8) * D_ + tx] = f2bfu(t[tx][ty + s*8]);
}

// ---- projh v-section -> vT[bh*64+dv][s] bf16 (per-(b,h) 64x64 transposes) ----
__global__ __launch_bounds__(256) void cvt_vT_kernel(const u16* __restrict__ projh, u16* __restrict__ vT){
  __shared__ u16 t[64*72];
  int s0 = blockIdx.x * 64;
  int bh = blockIdx.y;
  int b = bh >> 3, hh = bh & 7;
  int tid = threadIdx.x;
  {
    int row = tid >> 2, c16 = (tid & 3) * 16;
    const u16* sp = projh + ((size_t)(b*S_ + s0 + row)) * P_ + F_ + hh*64 + c16;
    short8 a = *(const short8*)sp;
    short8 bq = *(const short8*)(sp + 8);
    *(short8*)&t[row*72 + c16] = a;
    *(short8*)&t[row*72 + c16 + 8] = bq;
  }
  __syncthreads();
  {
    int dv = tid >> 2, sseg = (tid & 3) * 16;
    short8 o0, o1;
    #pragma unroll
    for (int j = 0; j < 8; j++) o0[j] = (short)t[(sseg + j)*72 + dv];
    #pragma unroll
    for (int j = 0; j < 8; j++) o1[j] = (short)t[(sseg + 8 + j)*72 + dv];
    u16* dp = vT + ((size_t)bh*64 + dv) * S_ + s0 + sseg;
    *(short8*)dp = o0;
    *(short8*)(dp + 8) = o1;
  }
}

// ---- LayerNorm over D=1024; one block per row; bf16 or fp32 out ----
__global__ __launch_bounds__(256) void ln_kernel(const float* __restrict__ xf,
    const float* __restrict__ w, const float* __restrict__ b,
    void* __restrict__ outp, float eps, int out_bf16){
  int row = blockIdx.x, tid = threadIdx.x;
  const float* xr = xf + (size_t)row * D_;
  float4 v = *(const float4*)(xr + tid * 4);
  float s  = v.x + v.y + v.z + v.w;
  float sq = v.x*v.x + v.y*v.y + v.z*v.z + v.w*v.w;
  #pragma unroll
  for (int off = 32; off; off >>= 1){ s += __shfl_down(s, off); sq += __shfl_down(sq, off); }
  __shared__ float red[8];
  __shared__ float stats[2];
  int wid = tid >> 6;
  if ((tid & 63) == 0){ red[wid] = s; red[4 + wid] = sq; }
  __syncthreads();
  if (tid == 0){
    float S1 = red[0] + red[1] + red[2] + red[3];
    float S2 = red[4] + red[5] + red[6] + red[7];
    float mu = S1 * (1.0f / D_);
    float var = S2 * (1.0f / D_) - mu * mu;
    stats[0] = mu; stats[1] = rsqrtf(var + eps);
  }
  __syncthreads();
  float mu = stats[0], rs = stats[1];
  int i = tid * 4;
  float4 wv = *(const float4*)(w + i);
  float4 bv = *(const float4*)(b + i);
  float o0 = (v.x - mu) * rs * wv.x + bv.x;
  float o1 = (v.y - mu) * rs * wv.y + bv.y;
  float o2 = (v.z - mu) * rs * wv.z + bv.z;
  float o3 = (v.w - mu) * rs * wv.w + bv.w;
  if (out_bf16){
    ushort4 o; o.x = f2bfu(o0); o.y = f2bfu(o1); o.z = f2bfu(o2); o.w = f2bfu(o3);
    *(ushort4*)((u16*)outp + (size_t)row * D_ + i) = o;
  } else {
    *(float4*)((float*)outp + (size_t)row * D_ + i) = make_float4(o0, o1, o2, o3);
  }
}

// ---- MFMA GEMM core: C(128x128) = A(128xK) @ Bt(128xK)^T, bf16 in, f32 acc ----
template<int KDIM>
__device__ __forceinline__ void gemm_mfma_core(const u16* __restrict__ A,
    const u16* __restrict__ Bt, u16* As, u16* Bs, int m0, int n0, v4f acc[4][4]){
  int tid = threadIdx.x;
  int w = tid >> 6, lane = tid & 63;
  int wm = w >> 1, wn = w & 1, quad = lane >> 4, l15 = lane & 15;
  int srow = lane >> 2, skoct = (lane & 3) * 8;
  for (int kt = 0; kt < KDIM; kt += 32){
    __syncthreads();
    #pragma unroll
    for (int s = 0; s < 2; s++){
      int g = w * 2 + s;
      gload16(A  + (size_t)(m0 + g*16 + srow) * KDIM + kt + skoct, As + g*512);
      gload16(Bt + (size_t)(n0 + g*16 + srow) * KDIM + kt + skoct, Bs + g*512);
    }
    __syncthreads();
    short8 af[4], bfr[4];
    #pragma unroll
    for (int i = 0; i < 4; i++)
      af[i] = *(const short8*)&As[(wm*64 + i*16 + l15)*32 + quad*8];
    #pragma unroll
    for (int j = 0; j < 4; j++)
      bfr[j] = *(const short8*)&Bs[(wn*64 + j*16 + l15)*32 + quad*8];
    #pragma unroll
    for (int i = 0; i < 4; i++)
      #pragma unroll
      for (int j = 0; j < 4; j++)
        acc[i][j] = __builtin_amdgcn_mfma_f32_16x16x32_bf16(
            __builtin_bit_cast(bf16x8, af[i]), __builtin_bit_cast(bf16x8, bfr[j]),
            acc[i][j], 0, 0, 0);
  }
}

// ---- projh = silu(h @ uvqk) -> bf16 ----
__global__ __launch_bounds__(256) void gemm_silu_mfma(const u16* __restrict__ A,
    const u16* __restrict__ Bt, u16* __restrict__ C){
  __shared__ u16 As[128*32], Bs[128*32];
  v4f acc[4][4];
  #pragma unroll
  for (int i = 0; i < 4; i++)
    #pragma unroll
    for (int j = 0; j < 4; j++) acc[i][j] = (v4f){0.f,0.f,0.f,0.f};
  int m0 = blockIdx.y * 128, n0 = blockIdx.x * 128;
  gemm_mfma_core<D_>(A, Bt, As, Bs, m0, n0, acc);
  int tid = threadIdx.x, w = tid >> 6, lane = tid & 63;
  int wm = w >> 1, wn = w & 1, quad = lane >> 4, l15 = lane & 15;
  #pragma unroll
  for (int i = 0; i < 4; i++)
    #pragma unroll
    for (int r = 0; r < 4; r++){
      int m = m0 + wm*64 + i*16 + quad*4 + r;
      u16* cp = C + (size_t)m * P_ + n0 + wn*64 + l15;
      #pragma unroll
      for (int j = 0; j < 4; j++)
        cp[j*16] = f2bfu(silu_fast(acc[i][j][r]));
    }
}

// ---- xf += udot @ owh^T + o_b ----
__global__ __launch_bounds__(256) void gemm_add_mfma(const u16* __restrict__ A,
    const u16* __restrict__ Bt, const float* __restrict__ bias, float* __restrict__ X){
  __shared__ u16 As[128*32], Bs[128*32];
  v4f acc[4][4];
  #pragma unroll
  for (int i = 0; i < 4; i++)
    #pragma unroll
    for (int j = 0; j < 4; j++) acc[i][j] = (v4f){0.f,0.f,0.f,0.f};
  int m0 = blockIdx.y * 128, n0 = blockIdx.x * 128;
  gemm_mfma_core<F_>(A, Bt, As, Bs, m0, n0, acc);
  int tid = threadIdx.x, w = tid >> 6, lane = tid & 63;
  int wm = w >> 1, wn = w & 1, quad = lane >> 4, l15 = lane & 15;
  float bj[4];
  #pragma unroll
  for (int j = 0; j < 4; j++) bj[j] = bias[n0 + wn*64 + j*16 + l15];
  #pragma unroll
  for (int i = 0; i < 4; i++)
    #pragma unroll
    for (int r = 0; r < 4; r++){
      int m = m0 + wm*64 + i*16 + quad*4 + r;
      float* xp = X + (size_t)m * D_ + n0 + wn*64 + l15;
      #pragma unroll
      for (int j = 0; j < 4; j++)
        xp[j*16] += acc[i][j][r] + bj[j];
    }
}

// ---- MFMA bf16 causal silu-attention, kt-split partials -> opart fp32 ----
// BARRIER-FREE: K/V fragments loaded per-lane global->VGPR (same addresses
// each lane's gload16 fetched in round 9 => bit-identical frags). Only LDS
// is Ps, wave-private write->read (validated in rounds 8/9 without barrier).
// Each wave runs its t-loop fully independently. Grid (S/128, B*H, 8).
__global__ __launch_bounds__(256) void attn_kernel(const u16* __restrict__ projh,
                                                   const u16* __restrict__ vT,
                                                   float* __restrict__ opart){
  __shared__ u16 Ps[128*72];       // bf16 scores [qrow][kt], stride 72; wave-private bands
  int qt = 15 - (int)blockIdx.x;   // heavy tiles first (128-row q-tiles)
  int z  = blockIdx.z;             // kt-split 0..7
  int ttop = 2*qt + 1;
  if (z > ttop) return;            // empty block (opart pre-zeroed)
  int bh = blockIdx.y;
  int b = bh >> 3, hh = bh & 7;
  int tid = threadIdx.x;
  int w = tid >> 6, lane = tid & 63, quad = lane >> 4, l15 = lane & 15;
  int s0 = qt * 128;
  const size_t bS = (size_t)b * S_;
  const int qoff = 2*F_ + hh*64, koff = 3*F_ + hh*64;
  const u16* vbase = vT + (size_t)bh * 64 * S_;

  bf16x8 aq[2][2];
  #pragma unroll
  for (int qh = 0; qh < 2; qh++){
    const u16* qp = projh + (bS + s0 + qh*64 + w*16 + l15) * P_ + qoff + quad*8;
    aq[qh][0] = __builtin_bit_cast(bf16x8, *(const short8*)qp);
    aq[qh][1] = __builtin_bit_cast(bf16x8, *(const short8*)(qp + 32));
  }

  v4f oacc[2][4];
  #pragma unroll
  for (int qh = 0; qh < 2; qh++)
    #pragma unroll
    for (int i = 0; i < 4; i++) oacc[qh][i] = (v4f){0.f, 0.f, 0.f, 0.f};

  for (int t = z; t <= ttop; t += 8){
    int t0 = t * 64;
    // K fragments: direct global->VGPR (per-lane 16B, bit-identical to r9 frags)
    short8 bk[4][2];
    #pragma unroll
    for (int ns = 0; ns < 4; ns++){
      const u16* kp = projh + (bS + t0 + ns*16 + l15) * P_ + koff + quad*8;
      bk[ns][0] = *(const short8*)kp;
      bk[ns][1] = *(const short8*)(kp + 32);
    }
    // V fragments: direct global->VGPR from pre-transposed vT
    short8 vf[4][2];
    #pragma unroll
    for (int ds = 0; ds < 4; ds++){
      const u16* vp = vbase + (size_t)(ds*16 + l15) * S_ + t0 + quad*8;
      vf[ds][0] = *(const short8*)vp;
      vf[ds][1] = *(const short8*)(vp + 32);
    }

    #pragma unroll
    for (int qh = 0; qh < 2; qh++){
      int dtile = 2*qt + qh;
      if (t > dtile) continue;
      v4f sacc[4];
      #pragma unroll
      for (int i = 0; i < 4; i++) sacc[i] = (v4f){0.f, 0.f, 0.f, 0.f};
      #pragma unroll
      for (int ns = 0; ns < 4; ns++){
        sacc[ns] = __builtin_amdgcn_mfma_f32_16x16x32_bf16(
            aq[qh][0], __builtin_bit_cast(bf16x8, bk[ns][0]), sacc[ns], 0, 0, 0);
        sacc[ns] = __builtin_amdgcn_mfma_f32_16x16x32_bf16(
            aq[qh][1], __builtin_bit_cast(bf16x8, bk[ns][1]), sacc[ns], 0, 0, 0);
      }

      bool diag = (t == dtile);
      #pragma unroll
      for (int ns = 0; ns < 4; ns++){
        #pragma unroll
        for (int r = 0; r < 4; r++){
          int rl = w*16 + quad*4 + r;
          int cl = ns*16 + l15;
          float p = silu_fast(sacc[ns][r]) * (1.0f / S_);
          if (diag && cl > rl) p = 0.0f;
          Ps[(qh*64 + rl)*72 + cl] = f2bfu(p);
        }
      }
      // wave-private bf16 readback = PV A-frag (in-order per-wave LDS; no barrier)
      #pragma unroll
      for (int kst = 0; kst < 2; kst++){
        short8 aps = *(const short8*)&Ps[(qh*64 + w*16 + l15)*72 + kst*32 + quad*8];
        bf16x8 ap = __builtin_bit_cast(bf16x8, aps);
        #pragma unroll
        for (int ds = 0; ds < 4; ds++){
          oacc[qh][ds] = __builtin_amdgcn_mfma_f32_16x16x32_bf16(
              ap, __builtin_bit_cast(bf16x8, vf[ds][kst]), oacc[qh][ds], 0, 0, 0);
        }
      }
    }
  }

  // epilogue: accumulate raw O partials (validated address mapping);
  // skip q-halves this z-slice never touched (z > dtile)
  #pragma unroll
  for (int qh = 0; qh < 2; qh++){
    if (z > 2*qt + qh) continue;
    #pragma unroll
    for (int r = 0; r < 4; r++){
      int sg = s0 + qh*64 + w*16 + quad*4 + r;
      float* op = opart + (bS + sg) * (size_t)F_ + hh*64 + l15;
      #pragma unroll
      for (int ds = 0; ds < 4; ds++)
        atomicAdd(op + ds*16, oacc[qh][ds][r]);
    }
  }
}

// ---- 64-dim no-affine norm + u-gate: opart fp32 -> udot bf16 ----
__global__ __launch_bounds__(256) void norm_gate_kernel(const float* __restrict__ opart,
    const u16* __restrict__ projh, u16* __restrict__ udot){
  int w = threadIdx.x >> 6, lane = threadIdx.x & 63;
  int sg = blockIdx.x * 4 + w;
  int hh = lane >> 3, seg = lane & 7;
  const float* op = opart + (size_t)sg * F_ + hh*64 + seg*8;
  v4f e0 = *(const v4f*)op;
  v4f e1 = *(const v4f*)(op + 4);
  float s  = e0[0]+e0[1]+e0[2]+e0[3] + e1[0]+e1[1]+e1[2]+e1[3];
  float sq = e0[0]*e0[0]+e0[1]*e0[1]+e0[2]*e0[2]+e0[3]*e0[3]
           + e1[0]*e1[0]+e1[1]*e1[1]+e1[2]*e1[2]+e1[3]*e1[3];
  #pragma unroll
  for (int m = 1; m < 8; m <<= 1){
    s  += __shfl_xor(s, m, 64);
    sq += __shfl_xor(sq, m, 64);
  }
  float mu = s * (1.0f/64.0f);
  float var = sq * (1.0f/64.0f) - mu*mu;
  float rs = rsqrtf(var + 1e-6f);
  const u16* up = projh + (size_t)sg * P_ + hh*64 + seg*8;
  short8 uv = *(const short8*)up;
  short8 ov;
  #pragma unroll
  for (int e = 0; e < 4; e++)
    ov[e] = (short)f2bfu((e0[e] - mu) * rs * bf2f((u16)uv[e]));
  #pragma unroll
  for (int e = 0; e < 4; e++)
    ov[4+e] = (short)f2bfu((e1[e] - mu) * rs * bf2f((u16)uv[4+e]));
  *(short8*)(udot + (size_t)sg * F_ + hh*64 + seg*8) = ov;
}

extern "C" void kernel_launch(void* const* d_in, const int* in_sizes, int n_in,
                              void* d_out, int out_size, void* d_ws, size_t ws_size,
                              hipStream_t stream){
  (void)in_sizes; (void)n_in; (void)out_size; (void)ws_size;
  const float* x     = (const float*)d_in[0];
  // d_in[1] = attn_mask (causal tril) -- hardcoded
  const float* uvqk  = (const float*)d_in[2];
  const float* o_w   = (const float*)d_in[3];
  const float* o_b   = (const float*)d_in[4];
  const float* ln_w  = (const float*)d_in[5];
  const float* ln_b  = (const float*)d_in[6];
  const float* lln_w = (const float*)d_in[7];
  const float* lln_b = (const float*)d_in[8];
  float* out = (float*)d_out;

  char* ws = (char*)d_ws;
  float* xf    = (float*)ws;                          // 16 MB
  u16*   h     = (u16*)(ws + (16u<<20));              //  8 MB (ln out)
  u16*   vT    = h;                                   //  4 MB alias: h dead after gemm_silu
  u16*   udot  = (u16*)(ws + (24u<<20));              //  4 MB
  u16*   projh = (u16*)(ws + (28u<<20));              // 16 MB
  u16*   uvqkT = (u16*)(ws + (44u<<20));              //  8 MB
  u16*   owh   = (u16*)(ws + (52u<<20));              //  2 MB
  float* opart = (float*)(ws + (54u<<20));            //  8 MB

  cvt_kernel<<<R_ * D_ / 1024, 256, 0, stream>>>(x, xf);
  cvt_uvqkT_kernel<<<dim3(P_/32, D_/32, L_), 256, 0, stream>>>(uvqk, uvqkT);
  cvt_bf16_kernel<<<L_ * D_ * F_ / 1024, 256, 0, stream>>>(o_w, owh);
  for (int l = 0; l < L_; l++){
    ln_kernel<<<R_, 256, 0, stream>>>(xf, ln_w + l * D_, ln_b + l * D_, h, 1e-6f, 1);
    gemm_silu_mfma<<<dim3(P_/128, R_/128), 256, 0, stream>>>(
        h, uvqkT + (size_t)l * P_ * D_, projh);
    cvt_vT_kernel<<<dim3(S_/64, B_*H_), 256, 0, stream>>>(projh, vT);
    zero_kernel<<<R_ * F_ / 1024, 256, 0, stream>>>(opart);
    attn_kernel<<<dim3(S_/128, B_*H_, 8), 256, 0, stream>>>(projh, vT, opart);
    norm_gate_kernel<<<R_/4, 256, 0, stream>>>(opart, projh, udot);
    gemm_add_mfma<<<dim3(D_/128, R_/128), 256, 0, stream>>>(
        udot, owh + (size_t)l * D_ * F_, o_b + l * D_, xf);
  }
  ln_kernel<<<R_, 256, 0, stream>>>(xf, lln_w, lln_b, out, 1e-8f, 0);
}

// Round 11
// 358.277 us; speedup vs baseline: 1.0869x; 1.0869x over previous
//
#include <hip/hip_runtime.h>

// HSTU block, B=2 S=2048 D=1024 H=8 head=64 L=2. Inputs/outputs fp32.
// ws (62 MB): xf f32(16M) | h bf16(8M; aliased by kpack 4M + vpack 4M)
//  | udot bf16(4M) | projh bf16(16M) | uvqkT bf16(8M) | owh bf16(2M) | opart f32(8M)
#define B_ 2
#define S_ 2048
#define D_ 1024
#define H_ 8
#define L_ 2
#define P_ 2048   // proj dim
#define F_ 512    // DL*H
#define R_ (B_*S_)

typedef unsigned short u16;
typedef unsigned int u32;
typedef __bf16 bf16;
typedef bf16 bf16x8 __attribute__((ext_vector_type(8)));
typedef short short8 __attribute__((ext_vector_type(8)));
typedef float v4f __attribute__((ext_vector_type(4)));

__device__ __forceinline__ float silu_fast(float x){
  float e = __expf(-x);
  return x * __builtin_amdgcn_rcpf(1.0f + e);
}
__device__ __forceinline__ float bf2f(u16 u){
  union { u32 i; float f; } x; x.i = ((u32)u) << 16; return x.f;
}
__device__ __forceinline__ u16 f2bfu(float f){
  union { float f; u32 i; } x; x.f = f;
  u32 r = x.i + 0x7fff + ((x.i >> 16) & 1);   // RNE
  return (u16)(r >> 16);
}
__device__ __forceinline__ void gload16(const u16* g, u16* l){
  __builtin_amdgcn_global_load_lds(
      (const __attribute__((address_space(1))) void*)g,
      (__attribute__((address_space(3))) void*)l, 16, 0, 0);
}

// ---- x copy ----
__global__ __launch_bounds__(256) void cvt_kernel(const float* __restrict__ x, float* __restrict__ xf){
  int i = (blockIdx.x * 256 + threadIdx.x) * 4;
  *(float4*)(xf + i) = *(const float4*)(x + i);
}

// ---- zero fp32 buffer ----
__global__ __launch_bounds__(256) void zero_kernel(float* __restrict__ p){
  int i = (blockIdx.x * 256 + threadIdx.x) * 4;
  *(float4*)(p + i) = make_float4(0.f, 0.f, 0.f, 0.f);
}

// ---- fp32 -> bf16 elementwise (o_w) ----
__global__ __launch_bounds__(256) void cvt_bf16_kernel(const float* __restrict__ src, u16* __restrict__ dst){
  int i = (blockIdx.x * 256 + threadIdx.x) * 4;
  float4 v = *(const float4*)(src + i);
  ushort4 o; o.x = f2bfu(v.x); o.y = f2bfu(v.y); o.z = f2bfu(v.z); o.w = f2bfu(v.w);
  *(ushort4*)(dst + i) = o;
}

// ---- uvqk (L,D,P) f32 -> uvqkT (L,P,D) bf16 ----
__global__ __launch_bounds__(256) void cvt_uvqkT_kernel(const float* __restrict__ uvqk, u16* __restrict__ ot){
  __shared__ float t[32][33];
  int l = blockIdx.z;
  int p0 = blockIdx.x * 32, d0 = blockIdx.y * 32;
  int tx = threadIdx.x & 31, ty = threadIdx.x >> 5;   // ty: 8 rows/pass
  const float* src = uvqk + ((size_t)l * D_ + d0) * P_ + p0;
  #pragma unroll
  for (int s = 0; s < 4; s++)
    t[ty + s*8][tx] = src[(size_t)(ty + s*8) * P_ + tx];
  __syncthreads();
  u16* dst = ot + ((size_t)l * P_ + p0) * D_ + d0;
  #pragma unroll
  for (int s = 0; s < 4; s++)
    dst[(size_t)(ty + s*8) * D_ + tx] = f2bfu(t[tx][ty + s*8]);
}

// ---- pack K and V tiles into fragment-linear order ----
// kpack[((bh*32+t)*8 + c)*512 + lane*8 + j] = K[t0+cns*16+l15][ckst*32+quad*8+j]
// vpack[same idx]                           = V[t0+ckst*32+quad*8+j][cns*16+l15]
// (c = cns*2+ckst; lane: quad=lane>>4, l15=lane&15) -- exactly the chunk/frag
// layout the round-9-validated attn kernel reads.
__global__ __launch_bounds__(256) void kvpack_kernel(const u16* __restrict__ projh,
    u16* __restrict__ kpack, u16* __restrict__ vpack){
  __shared__ u16 tls[64*72];
  int t = blockIdx.x, t0 = t * 64;
  int bh = blockIdx.y;
  int b = bh >> 3, hh = bh & 7;
  int tid = threadIdx.x;
  const size_t bS = (size_t)b * S_;
  const int voff = F_ + hh*64, koff = 3*F_ + hh*64;
  { // stage V 64x64 tile (row-major padded, coalesced reads)
    int row = tid >> 2, c16 = (tid & 3) * 16;
    const u16* sp = projh + (bS + t0 + row) * P_ + voff + c16;
    short8 a = *(const short8*)sp;
    short8 bq = *(const short8*)(sp + 8);
    *(short8*)&tls[row*72 + c16] = a;
    *(short8*)&tls[row*72 + c16 + 8] = bq;
  }
  __syncthreads();
  size_t obase = ((size_t)(bh*32 + t) * 8) * 512;
  #pragma unroll
  for (int pass = 0; pass < 2; pass++){
    int id = tid + pass * 256;          // 512 tasks: (c, lane)
    int c = id >> 6, lane = id & 63;
    int quad = lane >> 4, l15 = lane & 15;
    int cns = c >> 1, ckst = c & 1;
    // K: direct 16B gather -> contiguous write
    const u16* kp = projh + (bS + t0 + cns*16 + l15) * P_ + koff + ckst*32 + quad*8;
    *(short8*)(kpack + obase + (size_t)c*512 + lane*8) = *(const short8*)kp;
    // V: transpose gather from LDS tile -> contiguous write
    short8 vv;
    #pragma unroll
    for (int j = 0; j < 8; j++)
      vv[j] = (short)tls[(ckst*32 + quad*8 + j)*72 + cns*16 + l15];
    *(short8*)(vpack + obase + (size_t)c*512 + lane*8) = vv;
  }
}

// ---- LayerNorm over D=1024; one block per row; bf16 or fp32 out ----
__global__ __launch_bounds__(256) void ln_kernel(const float* __restrict__ xf,
    const float* __restrict__ w, const float* __restrict__ b,
    void* __restrict__ outp, float eps, int out_bf16){
  int row = blockIdx.x, tid = threadIdx.x;
  const float* xr = xf + (size_t)row * D_;
  float4 v = *(const float4*)(xr + tid * 4);
  float s  = v.x + v.y + v.z + v.w;
  float sq = v.x*v.x + v.y*v.y + v.z*v.z + v.w*v.w;
  #pragma unroll
  for (int off = 32; off; off >>= 1){ s += __shfl_down(s, off); sq += __shfl_down(sq, off); }
  __shared__ float red[8];
  __shared__ float stats[2];
  int wid = tid >> 6;
  if ((tid & 63) == 0){ red[wid] = s; red[4 + wid] = sq; }
  __syncthreads();
  if (tid == 0){
    float S1 = red[0] + red[1] + red[2] + red[3];
    float S2 = red[4] + red[5] + red[6] + red[7];
    float mu = S1 * (1.0f / D_);
    float var = S2 * (1.0f / D_) - mu * mu;
    stats[0] = mu; stats[1] = rsqrtf(var + eps);
  }
  __syncthreads();
  float mu = stats[0], rs = stats[1];
  int i = tid * 4;
  float4 wv = *(const float4*)(w + i);
  float4 bv = *(const float4*)(b + i);
  float o0 = (v.x - mu) * rs * wv.x + bv.x;
  float o1 = (v.y - mu) * rs * wv.y + bv.y;
  float o2 = (v.z - mu) * rs * wv.z + bv.z;
  float o3 = (v.w - mu) * rs * wv.w + bv.w;
  if (out_bf16){
    ushort4 o; o.x = f2bfu(o0); o.y = f2bfu(o1); o.z = f2bfu(o2); o.w = f2bfu(o3);
    *(ushort4*)((u16*)outp + (size_t)row * D_ + i) = o;
  } else {
    *(float4*)((float*)outp + (size_t)row * D_ + i) = make_float4(o0, o1, o2, o3);
  }
}

// ---- MFMA GEMM core: C(128x128) = A(128xK) @ Bt(128xK)^T, bf16 in, f32 acc ----
template<int KDIM>
__device__ __forceinline__ void gemm_mfma_core(const u16* __restrict__ A,
    const u16* __restrict__ Bt, u16* As, u16* Bs, int m0, int n0, v4f acc[4][4]){
  int tid = threadIdx.x;
  int w = tid >> 6, lane = tid & 63;
  int wm = w >> 1, wn = w & 1, quad = lane >> 4, l15 = lane & 15;
  int srow = lane >> 2, skoct = (lane & 3) * 8;
  for (int kt = 0; kt < KDIM; kt += 32){
    __syncthreads();
    #pragma unroll
    for (int s = 0; s < 2; s++){
      int g = w * 2 + s;
      gload16(A  + (size_t)(m0 + g*16 + srow) * KDIM + kt + skoct, As + g*512);
      gload16(Bt + (size_t)(n0 + g*16 + srow) * KDIM + kt + skoct, Bs + g*512);
    }
    __syncthreads();
    short8 af[4], bfr[4];
    #pragma unroll
    for (int i = 0; i < 4; i++)
      af[i] = *(const short8*)&As[(wm*64 + i*16 + l15)*32 + quad*8];
    #pragma unroll
    for (int j = 0; j < 4; j++)
      bfr[j] = *(const short8*)&Bs[(wn*64 + j*16 + l15)*32 + quad*8];
    #pragma unroll
    for (int i = 0; i < 4; i++)
      #pragma unroll
      for (int j = 0; j < 4; j++)
        acc[i][j] = __builtin_amdgcn_mfma_f32_16x16x32_bf16(
            __builtin_bit_cast(bf16x8, af[i]), __builtin_bit_cast(bf16x8, bfr[j]),
            acc[i][j], 0, 0, 0);
  }
}

// ---- projh = silu(h @ uvqk) -> bf16 ----
__global__ __launch_bounds__(256) void gemm_silu_mfma(const u16* __restrict__ A,
    const u16* __restrict__ Bt, u16* __restrict__ C){
  __shared__ u16 As[128*32], Bs[128*32];
  v4f acc[4][4];
  #pragma unroll
  for (int i = 0; i < 4; i++)
    #pragma unroll
    for (int j = 0; j < 4; j++) acc[i][j] = (v4f){0.f,0.f,0.f,0.f};
  int m0 = blockIdx.y * 128, n0 = blockIdx.x * 128;
  gemm_mfma_core<D_>(A, Bt, As, Bs, m0, n0, acc);
  int tid = threadIdx.x, w = tid >> 6, lane = tid & 63;
  int wm = w >> 1, wn = w & 1, quad = lane >> 4, l15 = lane & 15;
  #pragma unroll
  for (int i = 0; i < 4; i++)
    #pragma unroll
    for (int r = 0; r < 4; r++){
      int m = m0 + wm*64 + i*16 + quad*4 + r;
      u16* cp = C + (size_t)m * P_ + n0 + wn*64 + l15;
      #pragma unroll
      for (int j = 0; j < 4; j++)
        cp[j*16] = f2bfu(silu_fast(acc[i][j][r]));
    }
}

// ---- xf += udot @ owh^T + o_b ----
__global__ __launch_bounds__(256) void gemm_add_mfma(const u16* __restrict__ A,
    const u16* __restrict__ Bt, const float* __restrict__ bias, float* __restrict__ X){
  __shared__ u16 As[128*32], Bs[128*32];
  v4f acc[4][4];
  #pragma unroll
  for (int i = 0; i < 4; i++)
    #pragma unroll
    for (int j = 0; j < 4; j++) acc[i][j] = (v4f){0.f,0.f,0.f,0.f};
  int m0 = blockIdx.y * 128, n0 = blockIdx.x * 128;
  gemm_mfma_core<F_>(A, Bt, As, Bs, m0, n0, acc);
  int tid = threadIdx.x, w = tid >> 6, lane = tid & 63;
  int wm = w >> 1, wn = w & 1, quad = lane >> 4, l15 = lane & 15;
  float bj[4];
  #pragma unroll
  for (int j = 0; j < 4; j++) bj[j] = bias[n0 + wn*64 + j*16 + l15];
  #pragma unroll
  for (int i = 0; i < 4; i++)
    #pragma unroll
    for (int r = 0; r < 4; r++){
      int m = m0 + wm*64 + i*16 + quad*4 + r;
      float* xp = X + (size_t)m * D_ + n0 + wn*64 + l15;
      #pragma unroll
      for (int j = 0; j < 4; j++)
        xp[j*16] += acc[i][j][r] + bj[j];
    }
}

// ---- MFMA bf16 causal silu-attention, kt-split partials -> opart fp32 ----
// Round-9-validated dataflow; ONLY change: staging DMAs read the
// fragment-linear kpack/vpack buffers -> each gload16 is a fully
// contiguous 1KB transfer (was 64-way row-scattered).
__global__ __launch_bounds__(256) void attn_kernel(const u16* __restrict__ projh,
                                                   const u16* __restrict__ kpack,
                                                   const u16* __restrict__ vpack,
                                                   float* __restrict__ opart){
  __shared__ u16 ks[8*512];        // QK B-frags: chunk(ns,kst) = (ns*2+kst)*512
  __shared__ u16 vs[8*512];        // PV B-frags: chunk(ds,kst) = (ds*2+kst)*512
  __shared__ u16 Ps[128*72];       // bf16 scores [qrow][kt], stride 72
  int qt = 15 - (int)blockIdx.x;   // heavy tiles first (128-row q-tiles)
  int z  = blockIdx.z;             // kt-split 0..7
  int ttop = 2*qt + 1;
  if (z > ttop) return;            // empty block (opart pre-zeroed)
  int bh = blockIdx.y;
  int b = bh >> 3, hh = bh & 7;
  int tid = threadIdx.x;
  int w = tid >> 6, lane = tid & 63, quad = lane >> 4, l15 = lane & 15;
  int s0 = qt * 128;
  const size_t bS = (size_t)b * S_;
  const int qoff = 2*F_ + hh*64;

  bf16x8 aq[2][2];
  #pragma unroll
  for (int qh = 0; qh < 2; qh++){
    const u16* qp = projh + (bS + s0 + qh*64 + w*16 + l15) * P_ + qoff + quad*8;
    aq[qh][0] = __builtin_bit_cast(bf16x8, *(const short8*)qp);
    aq[qh][1] = __builtin_bit_cast(bf16x8, *(const short8*)(qp + 32));
  }

  v4f oacc[2][4];
  #pragma unroll
  for (int qh = 0; qh < 2; qh++)
    #pragma unroll
    for (int i = 0; i < 4; i++) oacc[qh][i] = (v4f){0.f, 0.f, 0.f, 0.f};

  for (int t = z; t <= ttop; t += 8){
    size_t pbase = ((size_t)(bh*32 + t) * 8) * 512;
    __syncthreads();
    #pragma unroll
    for (int cc = 0; cc < 2; cc++){
      int c = w + cc*4;            // chunk 0..7, wave-uniform
      gload16(kpack + pbase + (size_t)c*512 + lane*8, ks + c*512);
      gload16(vpack + pbase + (size_t)c*512 + lane*8, vs + c*512);
    }
    __syncthreads();

    int t0 = t * 64;
    #pragma unroll
    for (int qh = 0; qh < 2; qh++){
      int dtile = 2*qt + qh;
      if (t > dtile) continue;
      v4f sacc[4];
      #pragma unroll
      for (int i = 0; i < 4; i++) sacc[i] = (v4f){0.f, 0.f, 0.f, 0.f};
      #pragma unroll
      for (int ns = 0; ns < 4; ns++){
        bf16x8 bk0 = __builtin_bit_cast(bf16x8, *(const short8*)&ks[(ns*2+0)*512 + lane*8]);
        bf16x8 bk1 = __builtin_bit_cast(bf16x8, *(const short8*)&ks[(ns*2+1)*512 + lane*8]);
        sacc[ns] = __builtin_amdgcn_mfma_f32_16x16x32_bf16(aq[qh][0], bk0, sacc[ns], 0, 0, 0);
        sacc[ns] = __builtin_amdgcn_mfma_f32_16x16x32_bf16(aq[qh][1], bk1, sacc[ns], 0, 0, 0);
      }

      bool diag = (t == dtile);
      #pragma unroll
      for (int ns = 0; ns < 4; ns++){
        #pragma unroll
        for (int r = 0; r < 4; r++){
          int rl = w*16 + quad*4 + r;
          int cl = ns*16 + l15;
          float p = silu_fast(sacc[ns][r]) * (1.0f / S_);
          if (diag && cl > rl) p = 0.0f;
          Ps[(qh*64 + rl)*72 + cl] = f2bfu(p);
        }
      }
      // wave-private bf16 readback = PV A-frag (in-order per-wave LDS)
      #pragma unroll
      for (int kst = 0; kst < 2; kst++){
        short8 aps = *(const short8*)&Ps[(qh*64 + w*16 + l15)*72 + kst*32 + quad*8];
        bf16x8 ap = __builtin_bit_cast(bf16x8, aps);
        #pragma unroll
        for (int ds = 0; ds < 4; ds++){
          bf16x8 bv = __builtin_bit_cast(bf16x8, *(const short8*)&vs[(ds*2+kst)*512 + lane*8]);
          oacc[qh][ds] = __builtin_amdgcn_mfma_f32_16x16x32_bf16(ap, bv, oacc[qh][ds], 0, 0, 0);
        }
      }
    }
  }

  // epilogue: accumulate raw O partials; skip q-halves this z never touched
  #pragma unroll
  for (int qh = 0; qh < 2; qh++){
    if (z > 2*qt + qh) continue;
    #pragma unroll
    for (int r = 0; r < 4; r++){
      int sg = s0 + qh*64 + w*16 + quad*4 + r;
      float* op = opart + (bS + sg) * (size_t)F_ + hh*64 + l15;
      #pragma unroll
      for (int ds = 0; ds < 4; ds++)
        atomicAdd(op + ds*16, oacc[qh][ds][r]);
    }
  }
}

// ---- 64-dim no-affine norm + u-gate: opart fp32 -> udot bf16 ----
__global__ __launch_bounds__(256) void norm_gate_kernel(const float* __restrict__ opart,
    const u16* __restrict__ projh, u16* __restrict__ udot){
  int w = threadIdx.x >> 6, lane = threadIdx.x & 63;
  int sg = blockIdx.x * 4 + w;
  int hh = lane >> 3, seg = lane & 7;
  const float* op = opart + (size_t)sg * F_ + hh*64 + seg*8;
  v4f e0 = *(const v4f*)op;
  v4f e1 = *(const v4f*)(op + 4);
  float s  = e0[0]+e0[1]+e0[2]+e0[3] + e1[0]+e1[1]+e1[2]+e1[3];
  float sq = e0[0]*e0[0]+e0[1]*e0[1]+e0[2]*e0[2]+e0[3]*e0[3]
           + e1[0]*e1[0]+e1[1]*e1[1]+e1[2]*e1[2]+e1[3]*e1[3];
  #pragma unroll
  for (int m = 1; m < 8; m <<= 1){
    s  += __shfl_xor(s, m, 64);
    sq += __shfl_xor(sq, m, 64);
  }
  float mu = s * (1.0f/64.0f);
  float var = sq * (1.0f/64.0f) - mu*mu;
  float rs = rsqrtf(var + 1e-6f);
  const u16* up = projh + (size_t)sg * P_ + hh*64 + seg*8;
  short8 uv = *(const short8*)up;
  short8 ov;
  #pragma unroll
  for (int e = 0; e < 4; e++)
    ov[e] = (short)f2bfu((e0[e] - mu) * rs * bf2f((u16)uv[e]));
  #pragma unroll
  for (int e = 0; e < 4; e++)
    ov[4+e] = (short)f2bfu((e1[e] - mu) * rs * bf2f((u16)uv[4+e]));
  *(short8*)(udot + (size_t)sg * F_ + hh*64 + seg*8) = ov;
}

extern "C" void kernel_launch(void* const* d_in, const int* in_sizes, int n_in,
                              void* d_out, int out_size, void* d_ws, size_t ws_size,
                              hipStream_t stream){
  (void)in_sizes; (void)n_in; (void)out_size; (void)ws_size;
  const float* x     = (const float*)d_in[0];
  // d_in[1] = attn_mask (causal tril) -- hardcoded
  const float* uvqk  = (const float*)d_in[2];
  const float* o_w   = (const float*)d_in[3];
  const float* o_b   = (const float*)d_in[4];
  const float* ln_w  = (const float*)d_in[5];
  const float* ln_b  = (const float*)d_in[6];
  const float* lln_w = (const float*)d_in[7];
  const float* lln_b = (const float*)d_in[8];
  float* out = (float*)d_out;

  char* ws = (char*)d_ws;
  float* xf    = (float*)ws;                          // 16 MB
  u16*   h     = (u16*)(ws + (16u<<20));              //  8 MB (ln out)
  u16*   kpack = h;                                   //  4 MB alias (h dead after gemm_silu)
  u16*   vpack = (u16*)(ws + (20u<<20));              //  4 MB alias
  u16*   udot  = (u16*)(ws + (24u<<20));              //  4 MB
  u16*   projh = (u16*)(ws + (28u<<20));              // 16 MB
  u16*   uvqkT = (u16*)(ws + (44u<<20));              //  8 MB
  u16*   owh   = (u16*)(ws + (52u<<20));              //  2 MB
  float* opart = (float*)(ws + (54u<<20));            //  8 MB

  cvt_kernel<<<R_ * D_ / 1024, 256, 0, stream>>>(x, xf);
  cvt_uvqkT_kernel<<<dim3(P_/32, D_/32, L_), 256, 0, stream>>>(uvqk, uvqkT);
  cvt_bf16_kernel<<<L_ * D_ * F_ / 1024, 256, 0, stream>>>(o_w, owh);
  for (int l = 0; l < L_; l++){
    ln_kernel<<<R_, 256, 0, stream>>>(xf, ln_w + l * D_, ln_b + l * D_, h, 1e-6f, 1);
    gemm_silu_mfma<<<dim3(P_/128, R_/128), 256, 0, stream>>>(
        h, uvqkT + (size_t)l * P_ * D_, projh);
    kvpack_kernel<<<dim3(S_/64, B_*H_), 256, 0, stream>>>(projh, kpack, vpack);
    zero_kernel<<<R_ * F_ / 1024, 256, 0, stream>>>(opart);
    attn_kernel<<<dim3(S_/128, B_*H_, 8), 256, 0, stream>>>(projh, kpack, vpack, opart);
    norm_gate_kernel<<<R_/4, 256, 0, stream>>>(opart, projh, udot);
    gemm_add_mfma<<<dim3(D_/128, R_/128), 256, 0, stream>>>(
        udot, owh + (size_t)l * D_ * F_, o_b + l * D_, xf);
  }
  ln_kernel<<<R_, 256, 0, stream>>>(xf, lln_w, lln_b, out, 1e-8f, 0);
}

// Round 12
// 325.168 us; speedup vs baseline: 1.1976x; 1.1018x over previous
//
#include <hip/hip_runtime.h>

// HSTU block, B=2 S=2048 D=1024 H=8 head=64 L=2. Inputs/outputs fp32.
// ws (62 MB): xf f32(16M) | h bf16(8M; aliased by kpack 4M + vpack 4M)
//  | udot bf16(4M) | projh bf16(16M) | uvqkT bf16(8M) | owh bf16(2M) | opart f32(8M)
#define B_ 2
#define S_ 2048
#define D_ 1024
#define H_ 8
#define L_ 2
#define P_ 2048   // proj dim
#define F_ 512    // DL*H
#define R_ (B_*S_)

typedef unsigned short u16;
typedef unsigned int u32;
typedef __bf16 bf16;
typedef bf16 bf16x8 __attribute__((ext_vector_type(8)));
typedef short short8 __attribute__((ext_vector_type(8)));
typedef float v4f __attribute__((ext_vector_type(4)));

__device__ __forceinline__ float silu_fast(float x){
  float e = __expf(-x);
  return x * __builtin_amdgcn_rcpf(1.0f + e);
}
__device__ __forceinline__ float bf2f(u16 u){
  union { u32 i; float f; } x; x.i = ((u32)u) << 16; return x.f;
}
__device__ __forceinline__ u16 f2bfu(float f){
  union { float f; u32 i; } x; x.f = f;
  u32 r = x.i + 0x7fff + ((x.i >> 16) & 1);   // RNE
  return (u16)(r >> 16);
}
__device__ __forceinline__ void gload16(const u16* g, u16* l){
  __builtin_amdgcn_global_load_lds(
      (const __attribute__((address_space(1))) void*)g,
      (__attribute__((address_space(3))) void*)l, 16, 0, 0);
}

// ---- x copy ----
__global__ __launch_bounds__(256) void cvt_kernel(const float* __restrict__ x, float* __restrict__ xf){
  int i = (blockIdx.x * 256 + threadIdx.x) * 4;
  *(float4*)(xf + i) = *(const float4*)(x + i);
}

// ---- fp32 -> bf16 elementwise (o_w) ----
__global__ __launch_bounds__(256) void cvt_bf16_kernel(const float* __restrict__ src, u16* __restrict__ dst){
  int i = (blockIdx.x * 256 + threadIdx.x) * 4;
  float4 v = *(const float4*)(src + i);
  ushort4 o; o.x = f2bfu(v.x); o.y = f2bfu(v.y); o.z = f2bfu(v.z); o.w = f2bfu(v.w);
  *(ushort4*)(dst + i) = o;
}

// ---- uvqk (L,D,P) f32 -> uvqkT (L,P,D) bf16 ----
__global__ __launch_bounds__(256) void cvt_uvqkT_kernel(const float* __restrict__ uvqk, u16* __restrict__ ot){
  __shared__ float t[32][33];
  int l = blockIdx.z;
  int p0 = blockIdx.x * 32, d0 = blockIdx.y * 32;
  int tx = threadIdx.x & 31, ty = threadIdx.x >> 5;   // ty: 8 rows/pass
  const float* src = uvqk + ((size_t)l * D_ + d0) * P_ + p0;
  #pragma unroll
  for (int s = 0; s < 4; s++)
    t[ty + s*8][tx] = src[(size_t)(ty + s*8) * P_ + tx];
  __syncthreads();
  u16* dst = ot + ((size_t)l * P_ + p0) * D_ + d0;
  #pragma unroll
  for (int s = 0; s < 4; s++)
    dst[(size_t)(ty + s*8) * D_ + tx] = f2bfu(t[tx][ty + s*8]);
}

// ---- pack K and V tiles into fragment-linear order + zero opart slice ----
// kpack[((bh*32+t)*8 + c)*512 + lane*8 + j] = K[t0+cns*16+l15][ckst*32+quad*8+j]
// vpack[same idx]                           = V[t0+ckst*32+quad*8+j][cns*16+l15]
__global__ __launch_bounds__(256) void kvpack_kernel(const u16* __restrict__ projh,
    u16* __restrict__ kpack, u16* __restrict__ vpack, float* __restrict__ opart){
  __shared__ u16 tls[64*72];
  int t = blockIdx.x, t0 = t * 64;
  int bh = blockIdx.y;
  int b = bh >> 3, hh = bh & 7;
  int tid = threadIdx.x;
  const size_t bS = (size_t)b * S_;
  const int voff = F_ + hh*64, koff = 3*F_ + hh*64;
  { // zero this block's 16KB opart slice (4096 floats)
    float* zp = opart + (size_t)(bh*32 + t) * 4096 + tid * 16;
    #pragma unroll
    for (int i = 0; i < 4; i++)
      *(float4*)(zp + i*4) = make_float4(0.f, 0.f, 0.f, 0.f);
  }
  { // stage V 64x64 tile (row-major padded, coalesced reads)
    int row = tid >> 2, c16 = (tid & 3) * 16;
    const u16* sp = projh + (bS + t0 + row) * P_ + voff + c16;
    short8 a = *(const short8*)sp;
    short8 bq = *(const short8*)(sp + 8);
    *(short8*)&tls[row*72 + c16] = a;
    *(short8*)&tls[row*72 + c16 + 8] = bq;
  }
  __syncthreads();
  size_t obase = ((size_t)(bh*32 + t) * 8) * 512;
  #pragma unroll
  for (int pass = 0; pass < 2; pass++){
    int id = tid + pass * 256;          // 512 tasks: (c, lane)
    int c = id >> 6, lane = id & 63;
    int quad = lane >> 4, l15 = lane & 15;
    int cns = c >> 1, ckst = c & 1;
    const u16* kp = projh + (bS + t0 + cns*16 + l15) * P_ + koff + ckst*32 + quad*8;
    *(short8*)(kpack + obase + (size_t)c*512 + lane*8) = *(const short8*)kp;
    short8 vv;
    #pragma unroll
    for (int j = 0; j < 8; j++)
      vv[j] = (short)tls[(ckst*32 + quad*8 + j)*72 + cns*16 + l15];
    *(short8*)(vpack + obase + (size_t)c*512 + lane*8) = vv;
  }
}

// ---- LayerNorm over D=1024; one block per row; bf16 or fp32 out ----
__global__ __launch_bounds__(256) void ln_kernel(const float* __restrict__ xf,
    const float* __restrict__ w, const float* __restrict__ b,
    void* __restrict__ outp, float eps, int out_bf16){
  int row = blockIdx.x, tid = threadIdx.x;
  const float* xr = xf + (size_t)row * D_;
  float4 v = *(const float4*)(xr + tid * 4);
  float s  = v.x + v.y + v.z + v.w;
  float sq = v.x*v.x + v.y*v.y + v.z*v.z + v.w*v.w;
  #pragma unroll
  for (int off = 32; off; off >>= 1){ s += __shfl_down(s, off); sq += __shfl_down(sq, off); }
  __shared__ float red[8];
  __shared__ float stats[2];
  int wid = tid >> 6;
  if ((tid & 63) == 0){ red[wid] = s; red[4 + wid] = sq; }
  __syncthreads();
  if (tid == 0){
    float S1 = red[0] + red[1] + red[2] + red[3];
    float S2 = red[4] + red[5] + red[6] + red[7];
    float mu = S1 * (1.0f / D_);
    float var = S2 * (1.0f / D_) - mu * mu;
    stats[0] = mu; stats[1] = rsqrtf(var + eps);
  }
  __syncthreads();
  float mu = stats[0], rs = stats[1];
  int i = tid * 4;
  float4 wv = *(const float4*)(w + i);
  float4 bv = *(const float4*)(b + i);
  float o0 = (v.x - mu) * rs * wv.x + bv.x;
  float o1 = (v.y - mu) * rs * wv.y + bv.y;
  float o2 = (v.z - mu) * rs * wv.z + bv.z;
  float o3 = (v.w - mu) * rs * wv.w + bv.w;
  if (out_bf16){
    ushort4 o; o.x = f2bfu(o0); o.y = f2bfu(o1); o.z = f2bfu(o2); o.w = f2bfu(o3);
    *(ushort4*)((u16*)outp + (size_t)row * D_ + i) = o;
  } else {
    *(float4*)((float*)outp + (size_t)row * D_ + i) = make_float4(o0, o1, o2, o3);
  }
}

// ---- MFMA GEMM core: C(128x128) = A(128xK) @ Bt(128xK)^T, bf16 in, f32 acc ----
template<int KDIM>
__device__ __forceinline__ void gemm_mfma_core(const u16* __restrict__ A,
    const u16* __restrict__ Bt, u16* As, u16* Bs, int m0, int n0, v4f acc[4][4]){
  int tid = threadIdx.x;
  int w = tid >> 6, lane = tid & 63;
  int wm = w >> 1, wn = w & 1, quad = lane >> 4, l15 = lane & 15;
  int srow = lane >> 2, skoct = (lane & 3) * 8;
  for (int kt = 0; kt < KDIM; kt += 32){
    __syncthreads();
    #pragma unroll
    for (int s = 0; s < 2; s++){
      int g = w * 2 + s;
      gload16(A  + (size_t)(m0 + g*16 + srow) * KDIM + kt + skoct, As + g*512);
      gload16(Bt + (size_t)(n0 + g*16 + srow) * KDIM + kt + skoct, Bs + g*512);
    }
    __syncthreads();
    short8 af[4], bfr[4];
    #pragma unroll
    for (int i = 0; i < 4; i++)
      af[i] = *(const short8*)&As[(wm*64 + i*16 + l15)*32 + quad*8];
    #pragma unroll
    for (int j = 0; j < 4; j++)
      bfr[j] = *(const short8*)&Bs[(wn*64 + j*16 + l15)*32 + quad*8];
    #pragma unroll
    for (int i = 0; i < 4; i++)
      #pragma unroll
      for (int j = 0; j < 4; j++)
        acc[i][j] = __builtin_amdgcn_mfma_f32_16x16x32_bf16(
            __builtin_bit_cast(bf16x8, af[i]), __builtin_bit_cast(bf16x8, bfr[j]),
            acc[i][j], 0, 0, 0);
  }
}

// ---- projh = silu(h @ uvqk) -> bf16 ----
__global__ __launch_bounds__(256) void gemm_silu_mfma(const u16* __restrict__ A,
    const u16* __restrict__ Bt, u16* __restrict__ C){
  __shared__ u16 As[128*32], Bs[128*32];
  v4f acc[4][4];
  #pragma unroll
  for (int i = 0; i < 4; i++)
    #pragma unroll
    for (int j = 0; j < 4; j++) acc[i][j] = (v4f){0.f,0.f,0.f,0.f};
  int m0 = blockIdx.y * 128, n0 = blockIdx.x * 128;
  gemm_mfma_core<D_>(A, Bt, As, Bs, m0, n0, acc);
  int tid = threadIdx.x, w = tid >> 6, lane = tid & 63;
  int wm = w >> 1, wn = w & 1, quad = lane >> 4, l15 = lane & 15;
  #pragma unroll
  for (int i = 0; i < 4; i++)
    #pragma unroll
    for (int r = 0; r < 4; r++){
      int m = m0 + wm*64 + i*16 + quad*4 + r;
      u16* cp = C + (size_t)m * P_ + n0 + wn*64 + l15;
      #pragma unroll
      for (int j = 0; j < 4; j++)
        cp[j*16] = f2bfu(silu_fast(acc[i][j][r]));
    }
}

// ---- xf += udot @ owh^T + o_b ----
__global__ __launch_bounds__(256) void gemm_add_mfma(const u16* __restrict__ A,
    const u16* __restrict__ Bt, const float* __restrict__ bias, float* __restrict__ X){
  __shared__ u16 As[128*32], Bs[128*32];
  v4f acc[4][4];
  #pragma unroll
  for (int i = 0; i < 4; i++)
    #pragma unroll
    for (int j = 0; j < 4; j++) acc[i][j] = (v4f){0.f,0.f,0.f,0.f};
  int m0 = blockIdx.y * 128, n0 = blockIdx.x * 128;
  gemm_mfma_core<F_>(A, Bt, As, Bs, m0, n0, acc);
  int tid = threadIdx.x, w = tid >> 6, lane = tid & 63;
  int wm = w >> 1, wn = w & 1, quad = lane >> 4, l15 = lane & 15;
  float bj[4];
  #pragma unroll
  for (int j = 0; j < 4; j++) bj[j] = bias[n0 + wn*64 + j*16 + l15];
  #pragma unroll
  for (int i = 0; i < 4; i++)
    #pragma unroll
    for (int r = 0; r < 4; r++){
      int m = m0 + wm*64 + i*16 + quad*4 + r;
      float* xp = X + (size_t)m * D_ + n0 + wn*64 + l15;
      #pragma unroll
      for (int j = 0; j < 4; j++)
        xp[j*16] += acc[i][j][r] + bj[j];
    }
}

// ---- MFMA bf16 causal silu-attention, kt-split partials -> opart fp32 ----
// r11 dataflow with: Ps shrunk to one wave-private 64-row band reused across
// both qh (in-order per-wave LDS, LDS 34.8->25.2KB); PV B-frags (vf) hoisted
// to registers once per tile (halves vs reads, shortens PV chain); z-split 4
// (halves atomic write traffic). Grid (16, B*H, 4).
__global__ __launch_bounds__(256) void attn_kernel(const u16* __restrict__ projh,
                                                   const u16* __restrict__ kpack,
                                                   const u16* __restrict__ vpack,
                                                   float* __restrict__ opart){
  __shared__ u16 ks[8*512];        // QK B-frags: chunk(ns,kst) = (ns*2+kst)*512
  __shared__ u16 vs[8*512];        // PV B-frags: chunk(ds,kst) = (ds*2+kst)*512
  __shared__ u16 Ps[64*72];        // bf16 scores, wave-private 16-row bands, reused per qh
  int qt = 15 - (int)blockIdx.x;   // heavy tiles first (128-row q-tiles)
  int z  = blockIdx.z;             // kt-split 0..3
  int ttop = 2*qt + 1;
  if (z > ttop) return;            // empty block (opart pre-zeroed by kvpack)
  int bh = blockIdx.y;
  int b = bh >> 3, hh = bh & 7;
  int tid = threadIdx.x;
  int w = tid >> 6, lane = tid & 63, quad = lane >> 4, l15 = lane & 15;
  int s0 = qt * 128;
  const size_t bS = (size_t)b * S_;
  const int qoff = 2*F_ + hh*64;

  bf16x8 aq[2][2];
  #pragma unroll
  for (int qh = 0; qh < 2; qh++){
    const u16* qp = projh + (bS + s0 + qh*64 + w*16 + l15) * P_ + qoff + quad*8;
    aq[qh][0] = __builtin_bit_cast(bf16x8, *(const short8*)qp);
    aq[qh][1] = __builtin_bit_cast(bf16x8, *(const short8*)(qp + 32));
  }

  v4f oacc[2][4];
  #pragma unroll
  for (int qh = 0; qh < 2; qh++)
    #pragma unroll
    for (int i = 0; i < 4; i++) oacc[qh][i] = (v4f){0.f, 0.f, 0.f, 0.f};

  for (int t = z; t <= ttop; t += 4){
    size_t pbase = ((size_t)(bh*32 + t) * 8) * 512;
    __syncthreads();
    #pragma unroll
    for (int cc = 0; cc < 2; cc++){
      int c = w + cc*4;            // chunk 0..7, wave-uniform
      gload16(kpack + pbase + (size_t)c*512 + lane*8, ks + c*512);
      gload16(vpack + pbase + (size_t)c*512 + lane*8, vs + c*512);
    }
    __syncthreads();

    // hoist PV B-frags to registers once per tile (shared by both qh)
    short8 vf[4][2];
    #pragma unroll
    for (int ds = 0; ds < 4; ds++)
      #pragma unroll
      for (int kst = 0; kst < 2; kst++)
        vf[ds][kst] = *(const short8*)&vs[(ds*2+kst)*512 + lane*8];

    int t0 = t * 64;
    #pragma unroll
    for (int qh = 0; qh < 2; qh++){
      int dtile = 2*qt + qh;
      if (t > dtile) continue;
      v4f sacc[4];
      #pragma unroll
      for (int i = 0; i < 4; i++) sacc[i] = (v4f){0.f, 0.f, 0.f, 0.f};
      #pragma unroll
      for (int ns = 0; ns < 4; ns++){
        bf16x8 bk0 = __builtin_bit_cast(bf16x8, *(const short8*)&ks[(ns*2+0)*512 + lane*8]);
        bf16x8 bk1 = __builtin_bit_cast(bf16x8, *(const short8*)&ks[(ns*2+1)*512 + lane*8]);
        sacc[ns] = __builtin_amdgcn_mfma_f32_16x16x32_bf16(aq[qh][0], bk0, sacc[ns], 0, 0, 0);
        sacc[ns] = __builtin_amdgcn_mfma_f32_16x16x32_bf16(aq[qh][1], bk1, sacc[ns], 0, 0, 0);
      }

      bool diag = (t == dtile);
      #pragma unroll
      for (int ns = 0; ns < 4; ns++){
        #pragma unroll
        for (int r = 0; r < 4; r++){
          int rl = w*16 + quad*4 + r;
          int cl = ns*16 + l15;
          float p = silu_fast(sacc[ns][r]) * (1.0f / S_);
          if (diag && cl > rl) p = 0.0f;
          Ps[rl*72 + cl] = f2bfu(p);
        }
      }
      // wave-private bf16 readback = PV A-frag (in-order per-wave LDS)
      #pragma unroll
      for (int kst = 0; kst < 2; kst++){
        short8 aps = *(const short8*)&Ps[(w*16 + l15)*72 + kst*32 + quad*8];
        bf16x8 ap = __builtin_bit_cast(bf16x8, aps);
        #pragma unroll
        for (int ds = 0; ds < 4; ds++)
          oacc[qh][ds] = __builtin_amdgcn_mfma_f32_16x16x32_bf16(
              ap, __builtin_bit_cast(bf16x8, vf[ds][kst]), oacc[qh][ds], 0, 0, 0);
      }
    }
  }

  // epilogue: accumulate raw O partials; skip q-halves this z never touched
  #pragma unroll
  for (int qh = 0; qh < 2; qh++){
    if (z > 2*qt + qh) continue;
    #pragma unroll
    for (int r = 0; r < 4; r++){
      int sg = s0 + qh*64 + w*16 + quad*4 + r;
      float* op = opart + (bS + sg) * (size_t)F_ + hh*64 + l15;
      #pragma unroll
      for (int ds = 0; ds < 4; ds++)
        atomicAdd(op + ds*16, oacc[qh][ds][r]);
    }
  }
}

// ---- 64-dim no-affine norm + u-gate: opart fp32 -> udot bf16 ----
__global__ __launch_bounds__(256) void norm_gate_kernel(const float* __restrict__ opart,
    const u16* __restrict__ projh, u16* __restrict__ udot){
  int w = threadIdx.x >> 6, lane = threadIdx.x & 63;
  int sg = blockIdx.x * 4 + w;
  int hh = lane >> 3, seg = lane & 7;
  const float* op = opart + (size_t)sg * F_ + hh*64 + seg*8;
  v4f e0 = *(const v4f*)op;
  v4f e1 = *(const v4f*)(op + 4);
  float s  = e0[0]+e0[1]+e0[2]+e0[3] + e1[0]+e1[1]+e1[2]+e1[3];
  float sq = e0[0]*e0[0]+e0[1]*e0[1]+e0[2]*e0[2]+e0[3]*e0[3]
           + e1[0]*e1[0]+e1[1]*e1[1]+e1[2]*e1[2]+e1[3]*e1[3];
  #pragma unroll
  for (int m = 1; m < 8; m <<= 1){
    s  += __shfl_xor(s, m, 64);
    sq += __shfl_xor(sq, m, 64);
  }
  float mu = s * (1.0f/64.0f);
  float var = sq * (1.0f/64.0f) - mu*mu;
  float rs = rsqrtf(var + 1e-6f);
  const u16* up = projh + (size_t)sg * P_ + hh*64 + seg*8;
  short8 uv = *(const short8*)up;
  short8 ov;
  #pragma unroll
  for (int e = 0; e < 4; e++)
    ov[e] = (short)f2bfu((e0[e] - mu) * rs * bf2f((u16)uv[e]));
  #pragma unroll
  for (int e = 0; e < 4; e++)
    ov[4+e] = (short)f2bfu((e1[e] - mu) * rs * bf2f((u16)uv[4+e]));
  *(short8*)(udot + (size_t)sg * F_ + hh*64 + seg*8) = ov;
}

extern "C" void kernel_launch(void* const* d_in, const int* in_sizes, int n_in,
                              void* d_out, int out_size, void* d_ws, size_t ws_size,
                              hipStream_t stream){
  (void)in_sizes; (void)n_in; (void)out_size; (void)ws_size;
  const float* x     = (const float*)d_in[0];
  // d_in[1] = attn_mask (causal tril) -- hardcoded
  const float* uvqk  = (const float*)d_in[2];
  const float* o_w   = (const float*)d_in[3];
  const float* o_b   = (const float*)d_in[4];
  const float* ln_w  = (const float*)d_in[5];
  const float* ln_b  = (const float*)d_in[6];
  const float* lln_w = (const float*)d_in[7];
  const float* lln_b = (const float*)d_in[8];
  float* out = (float*)d_out;

  char* ws = (char*)d_ws;
  float* xf    = (float*)ws;                          // 16 MB
  u16*   h     = (u16*)(ws + (16u<<20));              //  8 MB (ln out)
  u16*   kpack = h;                                   //  4 MB alias (h dead after gemm_silu)
  u16*   vpack = (u16*)(ws + (20u<<20));              //  4 MB alias
  u16*   udot  = (u16*)(ws + (24u<<20));              //  4 MB
  u16*   projh = (u16*)(ws + (28u<<20));              // 16 MB
  u16*   uvqkT = (u16*)(ws + (44u<<20));              //  8 MB
  u16*   owh   = (u16*)(ws + (52u<<20));              //  2 MB
  float* opart = (float*)(ws + (54u<<20));            //  8 MB

  cvt_kernel<<<R_ * D_ / 1024, 256, 0, stream>>>(x, xf);
  cvt_uvqkT_kernel<<<dim3(P_/32, D_/32, L_), 256, 0, stream>>>(uvqk, uvqkT);
  cvt_bf16_kernel<<<L_ * D_ * F_ / 1024, 256, 0, stream>>>(o_w, owh);
  for (int l = 0; l < L_; l++){
    ln_kernel<<<R_, 256, 0, stream>>>(xf, ln_w + l * D_, ln_b + l * D_, h, 1e-6f, 1);
    gemm_silu_mfma<<<dim3(P_/128, R_/128), 256, 0, stream>>>(
        h, uvqkT + (size_t)l * P_ * D_, projh);
    kvpack_kernel<<<dim3(S_/64, B_*H_), 256, 0, stream>>>(projh, kpack, vpack, opart);
    attn_kernel<<<dim3(S_/128, B_*H_, 4), 256, 0, stream>>>(projh, kpack, vpack, opart);
    norm_gate_kernel<<<R_/4, 256, 0, stream>>>(opart, projh, udot);
    gemm_add_mfma<<<dim3(D_/128, R_/128), 256, 0, stream>>>(
        udot, owh + (size_t)l * D_ * F_, o_b + l * D_, xf);
  }
  ln_kernel<<<R_, 256, 0, stream>>>(xf, lln_w, lln_b, out, 1e-8f, 0);
}